// Round 9
// baseline (277.478 us; speedup 1.0000x reference)
//
#include <hip/hip_runtime.h>
#include <cstdint>

#define B_ 2
#define S_ 2048
#define D_ 1024
#define H_ 16

typedef __bf16 bf16x8 __attribute__((ext_vector_type(8)));
typedef __bf16 bf16x4 __attribute__((ext_vector_type(4)));
typedef float  f32x4  __attribute__((ext_vector_type(4)));

// async global->LDS, 16B per lane; LDS dest = wave-uniform base + lane*16 (HW)
__device__ __forceinline__ void g2l16(const void* g, void* l) {
  auto* gp = reinterpret_cast<const __attribute__((address_space(1))) uint32_t*>(
      reinterpret_cast<uintptr_t>(g));
  auto* lp = reinterpret_cast<__attribute__((address_space(3))) uint32_t*>(
      reinterpret_cast<uintptr_t>(l));
  __builtin_amdgcn_global_load_lds(gp, lp, 16, 0, 0);
}

__device__ __forceinline__ float exp2_hw(float x) {
#if __has_builtin(__builtin_amdgcn_exp2f)
  return __builtin_amdgcn_exp2f(x);
#else
  return __exp2f(x);
#endif
}

// ---------------- K0: fp32 -> bf16 conversion (WEIGHTS ONLY) ----------------
struct CvtArgs {
  const float* s[4];
  __bf16* d[4];
};

__global__ __launch_bounds__(256) void k_cvt(CvtArgs a) {
  int t = blockIdx.y;
  long base = ((long)blockIdx.x * blockDim.x + threadIdx.x) * 8;
  const float4* sp = (const float4*)(a.s[t] + base);
  float4 x = sp[0], y = sp[1];
  bf16x8 o;
  o[0] = (__bf16)x.x; o[1] = (__bf16)x.y; o[2] = (__bf16)x.z; o[3] = (__bf16)x.w;
  o[4] = (__bf16)y.x; o[5] = (__bf16)y.y; o[6] = (__bf16)y.z; o[7] = (__bf16)y.w;
  *(bf16x8*)(a.d[t] + base) = o;
}

// ---------------- K1: QKV projection GEMM, fp32 X input (R8 verbatim) -------
__global__ __launch_bounds__(256, 3) void k_proj(
    const float* __restrict__ Xq, const float* __restrict__ Xk, const float* __restrict__ Xv,
    const __bf16* __restrict__ Wq, const __bf16* __restrict__ Wk, const __bf16* __restrict__ Wv,
    const float* __restrict__ bq, const float* __restrict__ bk, const float* __restrict__ bv,
    __bf16* __restrict__ Oq, __bf16* __restrict__ Ok, __bf16* __restrict__ OvT)
{
  int o = (blockIdx.x % 96) * 8 + blockIdx.x / 96;  // bijective, 768 = 96*8
  int nb = o & 7, mb = (o >> 3) & 31, z = o >> 8;

  const float* X = (z == 0) ? Xq : (z == 1) ? Xk : Xv;
  const __bf16* W = (z == 0) ? Wq : (z == 1) ? Wk : Wv;
  const float* bias = (z == 0) ? bq : (z == 1) ? bk : bv;
  float scale = (z == 0) ? 0.180336880111183f : 1.0f;  // 0.125 * log2(e)

  __shared__ __align__(16) char smem[40960];
  bf16x8 (*As)[512] = (bf16x8(*)[512])smem;
  bf16x8 (*Bs)[512] = (bf16x8(*)[512])(smem + 16384);

  int t = threadIdx.x, lane = t & 63, w = t >> 6;
  int l15 = lane & 15, l4 = lane >> 4;
  int wr = w >> 1, wc = w & 1;
  int m0 = mb * 128, n0 = nb * 128;

  int arow = t >> 1, ac2 = (t & 1) * 2;
  const float* Xs = X + (size_t)(m0 + arow) * 1024 + (t & 1) * 16;
  int srow = t >> 2, sc = t & 3;
  const __bf16* Wsp = W + (size_t)(n0 + srow) * 1024 + sc * 8;
  int ldsoff = __builtin_amdgcn_readfirstlane(w * 1024);

  float4 a0, a1, a2, a3;

#define ALOAD(kt)                                                              \
  {                                                                            \
    const float4* ap = (const float4*)(Xs + (size_t)(kt) * 32);                \
    a0 = ap[0]; a1 = ap[1]; a2 = ap[2]; a3 = ap[3];                            \
  }
#define AWRITE(buf)                                                            \
  {                                                                            \
    bf16x8 lo, hi;                                                             \
    lo[0] = (__bf16)a0.x; lo[1] = (__bf16)a0.y; lo[2] = (__bf16)a0.z;          \
    lo[3] = (__bf16)a0.w; lo[4] = (__bf16)a1.x; lo[5] = (__bf16)a1.y;          \
    lo[6] = (__bf16)a1.z; lo[7] = (__bf16)a1.w;                                \
    hi[0] = (__bf16)a2.x; hi[1] = (__bf16)a2.y; hi[2] = (__bf16)a2.z;          \
    hi[3] = (__bf16)a2.w; hi[4] = (__bf16)a3.x; hi[5] = (__bf16)a3.y;          \
    hi[6] = (__bf16)a3.z; hi[7] = (__bf16)a3.w;                                \
    As[buf][arow * 4 + ac2] = lo;                                              \
    As[buf][arow * 4 + ac2 + 1] = hi;                                          \
  }
#define BSTG(buf, kt)                                                          \
  {                                                                            \
    _Pragma("unroll")                                                          \
    for (int i = 0; i < 2; ++i) {                                              \
      int lo_ = __builtin_amdgcn_readfirstlane(i * 4096 + ldsoff);             \
      g2l16(Wsp + (size_t)i * 64 * 1024 + (kt) * 32, (char*)Bs[buf] + lo_);    \
    }                                                                          \
  }

  f32x4 acc[4][4] = {};

  BSTG(0, 0)
  ALOAD(0)
  BSTG(1, 1)
  asm volatile("s_waitcnt vmcnt(2)" ::: "memory");
  AWRITE(0)
  ALOAD(1)
  asm volatile("s_waitcnt lgkmcnt(0)" ::: "memory");
  __builtin_amdgcn_s_barrier();
  __builtin_amdgcn_sched_barrier(0);

  int bring = 0;
  for (int kt = 0; kt < 32; ++kt) {
    int bcur = bring;
    int bp2 = (bring >= 1) ? bring - 1 : 2;
    int acur = kt & 1, anxt = acur ^ 1;
    if (kt + 2 < 32) BSTG(bp2, kt + 2)
    __builtin_amdgcn_sched_barrier(0);

    bf16x8 af[4], bfr[4];
#pragma unroll
    for (int i = 0; i < 4; ++i) af[i] = As[acur][(wr * 64 + i * 16 + l15) * 4 + l4];
#pragma unroll
    for (int j = 0; j < 4; ++j) bfr[j] = Bs[bcur][(wc * 64 + j * 16 + l15) * 4 + l4];
#pragma unroll
    for (int i = 0; i < 4; ++i)
#pragma unroll
      for (int j = 0; j < 4; ++j)
        acc[i][j] = __builtin_amdgcn_mfma_f32_16x16x32_bf16(af[i], bfr[j], acc[i][j], 0, 0, 0);
    __builtin_amdgcn_sched_barrier(0);

    if (kt + 1 < 32) {
      if (kt + 2 < 32) {
        asm volatile("s_waitcnt vmcnt(2)" ::: "memory");
      } else {
        asm volatile("s_waitcnt vmcnt(0)" ::: "memory");
      }
      AWRITE(anxt)
      if (kt + 2 < 32) ALOAD(kt + 2)
      asm volatile("s_waitcnt lgkmcnt(0)" ::: "memory");
      __builtin_amdgcn_s_barrier();
      __builtin_amdgcn_sched_barrier(0);
    }
    bring = (bring == 2) ? 0 : bring + 1;
  }
#undef ALOAD
#undef AWRITE
#undef BSTG

  if (z == 2) {
    __syncthreads();
    __bf16* Tt = (__bf16*)smem;
    const int LDT = 136;
    int b = m0 >> 11, ss0 = m0 & 2047;
#pragma unroll
    for (int p = 0; p < 2; ++p) {
      if (wc == p) {
#pragma unroll
        for (int j = 0; j < 4; ++j) {
          float bv_ = bias[n0 + p * 64 + j * 16 + l15];
#pragma unroll
          for (int i = 0; i < 4; ++i) {
            bf16x4 pv;
#pragma unroll
            for (int r = 0; r < 4; ++r) pv[r] = (__bf16)(acc[i][j][r] + bv_);
            *(bf16x4*)&Tt[(j * 16 + l15) * LDT + wr * 64 + i * 16 + l4 * 4] = pv;
          }
        }
      }
      __syncthreads();
      int h = (n0 >> 6) + p;
      __bf16* dst = OvT + ((size_t)(b * H_ + h) * 64) * S_ + ss0;
#pragma unroll
      for (int it = 0; it < 4; ++it) {
        int nl = it * 16 + (t >> 4);
        int mc = (t & 15) * 8;
        bf16x8 vv = *(bf16x8*)&Tt[nl * LDT + mc];
        *(bf16x8*)(dst + (size_t)nl * S_ + mc) = vv;
      }
      __syncthreads();
    }
  } else {
    __bf16* O = (z == 0) ? Oq : Ok;
#pragma unroll
    for (int j = 0; j < 4; ++j) {
      int col = n0 + wc * 64 + j * 16 + l15;
      float bv_ = bias[col];
      int h = col >> 6, hd = col & 63;
#pragma unroll
      for (int i = 0; i < 4; ++i) {
#pragma unroll
        for (int r = 0; r < 4; ++r) {
          int row = m0 + wr * 64 + i * 16 + l4 * 4 + r;
          int b = row >> 11, ss = row & 2047;
          float val = (acc[i][j][r] + bv_) * scale;
          O[(((size_t)b * H_ + h) * S_ + ss) * 64 + hd] = (__bf16)val;
        }
      }
    }
  }
}

// ---------------- K2: attention; 1024 threads, QBLK=256, 8 readers/head -----
__global__ __launch_bounds__(1024, 1) void k_attn(
    const __bf16* __restrict__ Qh, const __bf16* __restrict__ Kh,
    const __bf16* __restrict__ VhT, float* __restrict__ atten,
    __bf16* __restrict__ ctxb)
{
  __shared__ bf16x8 KVl[3][1024];  // 3 x 16KB stages (A: 128 keys; B: 64K + 64V)
  __shared__ bf16x8 Pl[16 * 176];  // per-wave p: [16 rows][11 chunks]

  int bid = blockIdx.x;
  int sb = (bid & 7) * 32 + (bid >> 3);  // XCD swizzle (256 = 8*32, bijective)
  int bh = sb >> 3, qt = sb & 7;
  int t = threadIdx.x, lane = t & 63, w = t >> 6;   // w in [0,16)
  int l15 = lane & 15, l4 = lane >> 4;
  int q0 = qt * 256 + w * 16;

  const __bf16* Qp = Qh + ((size_t)bh * S_ + q0) * 64;
  bf16x8 qf0 = *(const bf16x8*)(Qp + (size_t)l15 * 64 + l4 * 8);
  bf16x8 qf1 = *(const bf16x8*)(Qp + (size_t)l15 * 64 + 32 + l4 * 8);

  int wbase = __builtin_amdgcn_readfirstlane(w * 1024);

  // pass-A staging: thread covers K row r128 = t>>3 of the 128-key chunk
  int r128 = t >> 3, c8 = t & 7;
  int scsA = c8 ^ (r128 & 7);
  const __bf16* KpA = Kh + (size_t)bh * S_ * 64 + (size_t)r128 * 64 + scsA * 8;

  // pass-B staging: waves 0-7 stage K (64 rows), waves 8-15 stage V (64 rows)
  int rB = t >> 3;
  int rr = (rB < 64) ? rB : rB - 64;
  int scsB = c8 ^ (rr & 7);
  const __bf16* srcB = (rB < 64)
      ? (Kh + (size_t)bh * S_ * 64 + (size_t)rr * 64 + scsB * 8)
      : (VhT + (size_t)bh * 64 * S_ + (size_t)rr * S_ + scsB * 8);
  size_t stepB = (rB < 64) ? 4096 : 64;  // elems per kt

  // ---- pass A: softmax denominator; 16 iters x 128 keys, 3-deep ring ----
  float l_part[4] = {0.f, 0.f, 0.f, 0.f};

#define ASTAGE(buf, kt) g2l16(KpA + (size_t)(kt) * 8192, (char*)KVl[buf] + wbase);

  ASTAGE(0, 0)
  ASTAGE(1, 1)
  asm volatile("s_waitcnt vmcnt(1)" ::: "memory");
  __builtin_amdgcn_s_barrier();
  __builtin_amdgcn_sched_barrier(0);

  {
    int ring = 0;
    for (int kt = 0; kt < 16; ++kt) {
      int cur = ring;
      int rp2 = (ring == 0) ? 2 : ring - 1;
      if (kt + 2 < 16) ASTAGE(rp2, kt + 2)
      __builtin_amdgcn_sched_barrier(0);

#pragma unroll
      for (int t8 = 0; t8 < 8; ++t8) {
        int kr = t8 * 16 + l15;
        bf16x8 kf0 = KVl[cur][kr * 8 + ((l4) ^ (kr & 7))];
        bf16x8 kf1 = KVl[cur][kr * 8 + ((4 + l4) ^ (kr & 7))];
        f32x4 a_ = {0.f, 0.f, 0.f, 0.f};
        a_ = __builtin_amdgcn_mfma_f32_16x16x32_bf16(qf0, kf0, a_, 0, 0, 0);
        a_ = __builtin_amdgcn_mfma_f32_16x16x32_bf16(qf1, kf1, a_, 0, 0, 0);
#pragma unroll
        for (int r = 0; r < 4; ++r) l_part[r] += exp2_hw(a_[r]);
      }

      if (kt < 14) {
        asm volatile("s_waitcnt vmcnt(1)" ::: "memory");
        __builtin_amdgcn_s_barrier();
        __builtin_amdgcn_sched_barrier(0);
      } else if (kt == 14) {
        asm volatile("s_waitcnt vmcnt(0)" ::: "memory");
        __builtin_amdgcn_s_barrier();
        __builtin_amdgcn_sched_barrier(0);
      }
      ring = (ring == 2) ? 0 : ring + 1;
    }
  }
#undef ASTAGE

  float inv_l[4];
#pragma unroll
  for (int r = 0; r < 4; ++r) {
    float l = l_part[r];
    l += __shfl_xor(l, 1);
    l += __shfl_xor(l, 2);
    l += __shfl_xor(l, 4);
    l += __shfl_xor(l, 8);
    inv_l[r] = 1.0f / l;
  }

  // all waves done reading pass-A buffers before pass B overwrites them
  __builtin_amdgcn_s_barrier();
  __builtin_amdgcn_sched_barrier(0);

  // ---- pass B: write atten + accumulate ctx; 32 iters x 64 keys ----
  f32x4 ctx[4] = {};
  float* aRow = atten + ((size_t)bh * S_ + q0) * S_;
  __bf16* PlW = (__bf16*)(Pl + w * 176);

#define BSTAGE(buf, kt) g2l16(srcB + (size_t)(kt) * stepB, (char*)KVl[buf] + wbase);

  BSTAGE(0, 0)
  BSTAGE(1, 1)
  asm volatile("s_waitcnt vmcnt(1)" ::: "memory");
  __builtin_amdgcn_s_barrier();
  __builtin_amdgcn_sched_barrier(0);

  {
    int ring = 0;
    for (int kt = 0; kt < 32; ++kt) {
      int cur = ring;
      int rp2 = (ring == 0) ? 2 : ring - 1;
      if (kt + 2 < 32) BSTAGE(rp2, kt + 2)
      // pin: stage load issues BEFORE the 16 atten stores -> vmcnt counting holds
      __builtin_amdgcn_sched_barrier(0);

      f32x4 sc[4];
#pragma unroll
      for (int t8 = 0; t8 < 4; ++t8) {
        int kr = t8 * 16 + l15;
        bf16x8 kf0 = KVl[cur][kr * 8 + ((l4) ^ (kr & 7))];
        bf16x8 kf1 = KVl[cur][kr * 8 + ((4 + l4) ^ (kr & 7))];
        f32x4 a_ = {0.f, 0.f, 0.f, 0.f};
        a_ = __builtin_amdgcn_mfma_f32_16x16x32_bf16(qf0, kf0, a_, 0, 0, 0);
        a_ = __builtin_amdgcn_mfma_f32_16x16x32_bf16(qf1, kf1, a_, 0, 0, 0);
        sc[t8] = a_;
      }

#pragma unroll
      for (int t8 = 0; t8 < 4; ++t8) {
#pragma unroll
        for (int r = 0; r < 4; ++r) {
          float p = exp2_hw(sc[t8][r]) * inv_l[r];
          aRow[(size_t)(l4 * 4 + r) * S_ + kt * 64 + t8 * 16 + l15] = p;
          PlW[(l4 * 4 + r) * 88 + t8 * 16 + l15] = (__bf16)p;
        }
      }

#pragma unroll
      for (int kc = 0; kc < 2; ++kc) {
        bf16x8 pa = Pl[w * 176 + l15 * 11 + kc * 4 + l4];
#pragma unroll
        for (int dt = 0; dt < 4; ++dt) {
          int vr = dt * 16 + l15;
          bf16x8 vf = KVl[cur][512 + vr * 8 + ((kc * 4 + l4) ^ (vr & 7))];
          ctx[dt] = __builtin_amdgcn_mfma_f32_16x16x32_bf16(pa, vf, ctx[dt], 0, 0, 0);
        }
      }

      // in-order vmcnt: drain through L(t+1) while streaming current stores.
      // kt=0: L1,L2,St0(16)=18 -> 17 | steady: L(t+1),St(t-1)16,L(t+2),St(t)16=34 -> 33
      // kt=30: L31,St(29)16,St(30)16=33 -> 32 | kt=31: none
      if (kt == 0) {
        asm volatile("s_waitcnt vmcnt(17)" ::: "memory");
        __builtin_amdgcn_s_barrier();
        __builtin_amdgcn_sched_barrier(0);
      } else if (kt < 30) {
        asm volatile("s_waitcnt vmcnt(33)" ::: "memory");
        __builtin_amdgcn_s_barrier();
        __builtin_amdgcn_sched_barrier(0);
      } else if (kt == 30) {
        asm volatile("s_waitcnt vmcnt(32)" ::: "memory");
        __builtin_amdgcn_s_barrier();
        __builtin_amdgcn_sched_barrier(0);
      }
      ring = (ring == 2) ? 0 : ring + 1;
    }
  }
#undef BSTAGE

  // epilogue: ctx -> ctxb [B,S,H*64] bf16
  int b = bh >> 4, h = bh & 15;
#pragma unroll
  for (int dt = 0; dt < 4; ++dt) {
#pragma unroll
    for (int r = 0; r < 4; ++r) {
      size_t row = (size_t)b * S_ + q0 + l4 * 4 + r;
      ctxb[row * D_ + h * 64 + dt * 16 + l15] = (__bf16)ctx[dt][r];
    }
  }
}

// ---------------- K3: output projection -> fp32 d_out (R8 verbatim) --------
__global__ __launch_bounds__(256, 3) void k_out(
    const __bf16* __restrict__ X, const __bf16* __restrict__ W,
    const float* __restrict__ bias, float* __restrict__ O)
{
  __shared__ bf16x8 As[3][512];
  __shared__ bf16x8 Bs[3][512];

  int o = (blockIdx.x % 32) * 8 + blockIdx.x / 32;  // bijective, 256 = 32*8
  int nb = o & 7, mb = o >> 3;

  int t = threadIdx.x, lane = t & 63, w = t >> 6;
  int l15 = lane & 15, l4 = lane >> 4;
  int wr = w >> 1, wc = w & 1;
  int m0 = mb * 128, n0 = nb * 128;

  int srow = t >> 2, sc = t & 3;
  int ldsoff = __builtin_amdgcn_readfirstlane(w * 1024);
  const __bf16* Xs = X + (size_t)(m0 + srow) * 1024 + sc * 8;
  const __bf16* Wsp = W + (size_t)(n0 + srow) * 1024 + sc * 8;

#define PSTAGE(buf, kt)                                                        \
  {                                                                            \
    _Pragma("unroll")                                                          \
    for (int i = 0; i < 2; ++i) {                                              \
      int lo = __builtin_amdgcn_readfirstlane(i * 4096 + ldsoff);              \
      g2l16(Xs + (size_t)i * 64 * 1024 + (kt) * 32, (char*)As[buf] + lo);      \
      g2l16(Wsp + (size_t)i * 64 * 1024 + (kt) * 32, (char*)Bs[buf] + lo);     \
    }                                                                          \
  }

  f32x4 acc[4][4] = {};

  PSTAGE(0, 0)
  PSTAGE(1, 1)
  asm volatile("s_waitcnt vmcnt(4)" ::: "memory");
  __builtin_amdgcn_s_barrier();
  __builtin_amdgcn_sched_barrier(0);

  int ring = 0;
  for (int kt = 0; kt < 32; ++kt) {
    int cur = ring;
    int rp2 = (ring == 0) ? 2 : ring - 1;
    if (kt + 2 < 32) PSTAGE(rp2, kt + 2)
    __builtin_amdgcn_sched_barrier(0);

    bf16x8 af[4], bfr[4];
#pragma unroll
    for (int i = 0; i < 4; ++i) af[i] = As[cur][(wr * 64 + i * 16 + l15) * 4 + l4];
#pragma unroll
    for (int j = 0; j < 4; ++j) bfr[j] = Bs[cur][(wc * 64 + j * 16 + l15) * 4 + l4];
#pragma unroll
    for (int i = 0; i < 4; ++i)
#pragma unroll
      for (int j = 0; j < 4; ++j)
        acc[i][j] = __builtin_amdgcn_mfma_f32_16x16x32_bf16(af[i], bfr[j], acc[i][j], 0, 0, 0);

    if (kt < 30) {
      asm volatile("s_waitcnt vmcnt(4)" ::: "memory");
      __builtin_amdgcn_s_barrier();
      __builtin_amdgcn_sched_barrier(0);
    } else if (kt == 30) {
      asm volatile("s_waitcnt vmcnt(0)" ::: "memory");
      __builtin_amdgcn_s_barrier();
      __builtin_amdgcn_sched_barrier(0);
    }
    ring = (ring == 2) ? 0 : ring + 1;
  }
#undef PSTAGE

#pragma unroll
  for (int j = 0; j < 4; ++j) {
    int col = n0 + wc * 64 + j * 16 + l15;
    float bv_ = bias[col];
#pragma unroll
    for (int i = 0; i < 4; ++i) {
#pragma unroll
      for (int r = 0; r < 4; ++r) {
        int row = m0 + wr * 64 + i * 16 + l4 * 4 + r;
        O[(size_t)row * 1024 + col] = acc[i][j][r] + bv_;
      }
    }
  }
}

// ---------------- launch ----------------
extern "C" void kernel_launch(void* const* d_in, const int* in_sizes, int n_in,
                              void* d_out, int out_size, void* d_ws, size_t ws_size,
                              hipStream_t stream)
{
  const float* q  = (const float*)d_in[0];
  const float* k  = (const float*)d_in[1];
  const float* v  = (const float*)d_in[2];
  const float* Wq = (const float*)d_in[3];
  const float* bq = (const float*)d_in[4];
  const float* Wk = (const float*)d_in[5];
  const float* bk = (const float*)d_in[6];
  const float* Wv = (const float*)d_in[7];
  const float* bv = (const float*)d_in[8];
  const float* Wo = (const float*)d_in[9];
  const float* bo = (const float*)d_in[10];

  const size_t NBSD = (size_t)B_ * S_ * D_;   // 4194304
  const size_t NDD  = (size_t)D_ * D_;        // 1048576

  float* out = (float*)d_out;
  float* atten = out + NBSD;

  if (ws_size < (4 * NDD + 4 * NBSD) * 2) return;  // ~41.9 MB needed

  __bf16* ws = (__bf16*)d_ws;
  __bf16* Wqb = ws;
  __bf16* Wkb = Wqb + NDD;
  __bf16* Wvb = Wkb + NDD;
  __bf16* Wob = Wvb + NDD;
  __bf16* Qh  = Wob + NDD;
  __bf16* Kh  = Qh + NBSD;
  __bf16* VhT = Kh + NBSD;
  __bf16* ctxb = VhT + NBSD;

  CvtArgs ca;
  ca.s[0] = Wq; ca.d[0] = Wqb;
  ca.s[1] = Wk; ca.d[1] = Wkb;
  ca.s[2] = Wv; ca.d[2] = Wvb;
  ca.s[3] = Wo; ca.d[3] = Wob;

  k_cvt<<<dim3(512, 4), 256, 0, stream>>>(ca);
  k_proj<<<dim3(768), 256, 0, stream>>>(q, k, v, Wqb, Wkb, Wvb,
                                        bq, bk, bv, Qh, Kh, VhT);
  k_attn<<<dim3(256), 1024, 0, stream>>>(Qh, Kh, VhT, atten, ctxb);
  k_out<<<dim3(256), 256, 0, stream>>>(ctxb, Wob, bo, out);
}

// Round 10
// 248.505 us; speedup vs baseline: 1.1166x; 1.1166x over previous
//
#include <hip/hip_runtime.h>
#include <cstdint>

#define B_ 2
#define S_ 2048
#define D_ 1024
#define H_ 16

typedef __bf16 bf16x8 __attribute__((ext_vector_type(8)));
typedef __bf16 bf16x4 __attribute__((ext_vector_type(4)));
typedef float  f32x4  __attribute__((ext_vector_type(4)));

// async global->LDS, 16B per lane; LDS dest = wave-uniform base + lane*16 (HW)
__device__ __forceinline__ void g2l16(const void* g, void* l) {
  auto* gp = reinterpret_cast<const __attribute__((address_space(1))) uint32_t*>(
      reinterpret_cast<uintptr_t>(g));
  auto* lp = reinterpret_cast<__attribute__((address_space(3))) uint32_t*>(
      reinterpret_cast<uintptr_t>(l));
  __builtin_amdgcn_global_load_lds(gp, lp, 16, 0, 0);
}

__device__ __forceinline__ float exp2_hw(float x) {
#if __has_builtin(__builtin_amdgcn_exp2f)
  return __builtin_amdgcn_exp2f(x);
#else
  return __exp2f(x);
#endif
}

// ---------------- K0: fp32 -> bf16 conversion (WEIGHTS ONLY) ----------------
struct CvtArgs {
  const float* s[4];
  __bf16* d[4];
};

__global__ __launch_bounds__(256) void k_cvt(CvtArgs a) {
  int t = blockIdx.y;
  long base = ((long)blockIdx.x * blockDim.x + threadIdx.x) * 8;
  const float4* sp = (const float4*)(a.s[t] + base);
  float4 x = sp[0], y = sp[1];
  bf16x8 o;
  o[0] = (__bf16)x.x; o[1] = (__bf16)x.y; o[2] = (__bf16)x.z; o[3] = (__bf16)x.w;
  o[4] = (__bf16)y.x; o[5] = (__bf16)y.y; o[6] = (__bf16)y.z; o[7] = (__bf16)y.w;
  *(bf16x8*)(a.d[t] + base) = o;
}

// ---------------- K1: QKV projection GEMM, fp32 X input (R8 verbatim) -------
__global__ __launch_bounds__(256, 3) void k_proj(
    const float* __restrict__ Xq, const float* __restrict__ Xk, const float* __restrict__ Xv,
    const __bf16* __restrict__ Wq, const __bf16* __restrict__ Wk, const __bf16* __restrict__ Wv,
    const float* __restrict__ bq, const float* __restrict__ bk, const float* __restrict__ bv,
    __bf16* __restrict__ Oq, __bf16* __restrict__ Ok, __bf16* __restrict__ OvT)
{
  int o = (blockIdx.x % 96) * 8 + blockIdx.x / 96;  // bijective, 768 = 96*8
  int nb = o & 7, mb = (o >> 3) & 31, z = o >> 8;

  const float* X = (z == 0) ? Xq : (z == 1) ? Xk : Xv;
  const __bf16* W = (z == 0) ? Wq : (z == 1) ? Wk : Wv;
  const float* bias = (z == 0) ? bq : (z == 1) ? bk : bv;
  float scale = (z == 0) ? 0.180336880111183f : 1.0f;  // 0.125 * log2(e)

  __shared__ __align__(16) char smem[40960];
  bf16x8 (*As)[512] = (bf16x8(*)[512])smem;
  bf16x8 (*Bs)[512] = (bf16x8(*)[512])(smem + 16384);

  int t = threadIdx.x, lane = t & 63, w = t >> 6;
  int l15 = lane & 15, l4 = lane >> 4;
  int wr = w >> 1, wc = w & 1;
  int m0 = mb * 128, n0 = nb * 128;

  int arow = t >> 1, ac2 = (t & 1) * 2;
  const float* Xs = X + (size_t)(m0 + arow) * 1024 + (t & 1) * 16;
  int srow = t >> 2, sc = t & 3;
  const __bf16* Wsp = W + (size_t)(n0 + srow) * 1024 + sc * 8;
  int ldsoff = __builtin_amdgcn_readfirstlane(w * 1024);

  float4 a0, a1, a2, a3;

#define ALOAD(kt)                                                              \
  {                                                                            \
    const float4* ap = (const float4*)(Xs + (size_t)(kt) * 32);                \
    a0 = ap[0]; a1 = ap[1]; a2 = ap[2]; a3 = ap[3];                            \
  }
#define AWRITE(buf)                                                            \
  {                                                                            \
    bf16x8 lo, hi;                                                             \
    lo[0] = (__bf16)a0.x; lo[1] = (__bf16)a0.y; lo[2] = (__bf16)a0.z;          \
    lo[3] = (__bf16)a0.w; lo[4] = (__bf16)a1.x; lo[5] = (__bf16)a1.y;          \
    lo[6] = (__bf16)a1.z; lo[7] = (__bf16)a1.w;                                \
    hi[0] = (__bf16)a2.x; hi[1] = (__bf16)a2.y; hi[2] = (__bf16)a2.z;          \
    hi[3] = (__bf16)a2.w; hi[4] = (__bf16)a3.x; hi[5] = (__bf16)a3.y;          \
    hi[6] = (__bf16)a3.z; hi[7] = (__bf16)a3.w;                                \
    As[buf][arow * 4 + ac2] = lo;                                              \
    As[buf][arow * 4 + ac2 + 1] = hi;                                          \
  }
#define BSTG(buf, kt)                                                          \
  {                                                                            \
    _Pragma("unroll")                                                          \
    for (int i = 0; i < 2; ++i) {                                              \
      int lo_ = __builtin_amdgcn_readfirstlane(i * 4096 + ldsoff);             \
      g2l16(Wsp + (size_t)i * 64 * 1024 + (kt) * 32, (char*)Bs[buf] + lo_);    \
    }                                                                          \
  }

  f32x4 acc[4][4] = {};

  BSTG(0, 0)
  ALOAD(0)
  BSTG(1, 1)
  asm volatile("s_waitcnt vmcnt(2)" ::: "memory");
  AWRITE(0)
  ALOAD(1)
  asm volatile("s_waitcnt lgkmcnt(0)" ::: "memory");
  __builtin_amdgcn_s_barrier();
  __builtin_amdgcn_sched_barrier(0);

  int bring = 0;
  for (int kt = 0; kt < 32; ++kt) {
    int bcur = bring;
    int bp2 = (bring >= 1) ? bring - 1 : 2;
    int acur = kt & 1, anxt = acur ^ 1;
    if (kt + 2 < 32) BSTG(bp2, kt + 2)
    __builtin_amdgcn_sched_barrier(0);

    bf16x8 af[4], bfr[4];
#pragma unroll
    for (int i = 0; i < 4; ++i) af[i] = As[acur][(wr * 64 + i * 16 + l15) * 4 + l4];
#pragma unroll
    for (int j = 0; j < 4; ++j) bfr[j] = Bs[bcur][(wc * 64 + j * 16 + l15) * 4 + l4];
#pragma unroll
    for (int i = 0; i < 4; ++i)
#pragma unroll
      for (int j = 0; j < 4; ++j)
        acc[i][j] = __builtin_amdgcn_mfma_f32_16x16x32_bf16(af[i], bfr[j], acc[i][j], 0, 0, 0);
    __builtin_amdgcn_sched_barrier(0);

    if (kt + 1 < 32) {
      if (kt + 2 < 32) {
        asm volatile("s_waitcnt vmcnt(2)" ::: "memory");
      } else {
        asm volatile("s_waitcnt vmcnt(0)" ::: "memory");
      }
      AWRITE(anxt)
      if (kt + 2 < 32) ALOAD(kt + 2)
      asm volatile("s_waitcnt lgkmcnt(0)" ::: "memory");
      __builtin_amdgcn_s_barrier();
      __builtin_amdgcn_sched_barrier(0);
    }
    bring = (bring == 2) ? 0 : bring + 1;
  }
#undef ALOAD
#undef AWRITE
#undef BSTG

  if (z == 2) {
    __syncthreads();
    __bf16* Tt = (__bf16*)smem;
    const int LDT = 136;
    int b = m0 >> 11, ss0 = m0 & 2047;
#pragma unroll
    for (int p = 0; p < 2; ++p) {
      if (wc == p) {
#pragma unroll
        for (int j = 0; j < 4; ++j) {
          float bv_ = bias[n0 + p * 64 + j * 16 + l15];
#pragma unroll
          for (int i = 0; i < 4; ++i) {
            bf16x4 pv;
#pragma unroll
            for (int r = 0; r < 4; ++r) pv[r] = (__bf16)(acc[i][j][r] + bv_);
            *(bf16x4*)&Tt[(j * 16 + l15) * LDT + wr * 64 + i * 16 + l4 * 4] = pv;
          }
        }
      }
      __syncthreads();
      int h = (n0 >> 6) + p;
      __bf16* dst = OvT + ((size_t)(b * H_ + h) * 64) * S_ + ss0;
#pragma unroll
      for (int it = 0; it < 4; ++it) {
        int nl = it * 16 + (t >> 4);
        int mc = (t & 15) * 8;
        bf16x8 vv = *(bf16x8*)&Tt[nl * LDT + mc];
        *(bf16x8*)(dst + (size_t)nl * S_ + mc) = vv;
      }
      __syncthreads();
    }
  } else {
    __bf16* O = (z == 0) ? Oq : Ok;
#pragma unroll
    for (int j = 0; j < 4; ++j) {
      int col = n0 + wc * 64 + j * 16 + l15;
      float bv_ = bias[col];
      int h = col >> 6, hd = col & 63;
#pragma unroll
      for (int i = 0; i < 4; ++i) {
#pragma unroll
        for (int r = 0; r < 4; ++r) {
          int row = m0 + wr * 64 + i * 16 + l4 * 4 + r;
          int b = row >> 11, ss = row & 2047;
          float val = (acc[i][j][r] + bv_) * scale;
          O[(((size_t)b * H_ + h) * S_ + ss) * 64 + hd] = (__bf16)val;
        }
      }
    }
  }
}

// ---------------- K2: attention; R8 geometry + SWAPPED QK fragment ----------
// mfma(K,Q): lane holds score[q=l15][k = t8*16 + l4*4 + r] -> 4 consecutive k
// per lane: dwordx4 atten stores, ds_write_b64 P staging, scalar inv_l.
// Pl layout [q=16][88] unchanged -> P reads / PV / ctx epilogue identical.
__global__ __launch_bounds__(512, 4) void k_attn(
    const __bf16* __restrict__ Qh, const __bf16* __restrict__ Kh,
    const __bf16* __restrict__ VhT, float* __restrict__ atten,
    __bf16* __restrict__ ctxb)
{
  __shared__ bf16x8 KVl[3][1024];  // 3 x 16KB stages (A: 128 keys; B: 64K + 64V)
  __shared__ bf16x8 Pl[8 * 176];   // per-wave p: [16 q rows][88 bf16 stride]

  int bid = blockIdx.x;
  int sb = (bid & 7) * 64 + (bid >> 3);  // XCD swizzle (512 = 8*64, bijective)
  int bh = sb >> 4, qt = sb & 15;
  int t = threadIdx.x, lane = t & 63, w = t >> 6;
  int l15 = lane & 15, l4 = lane >> 4;
  int q0 = qt * 128 + w * 16;

  const __bf16* Qp = Qh + ((size_t)bh * S_ + q0) * 64;
  bf16x8 qf0 = *(const bf16x8*)(Qp + (size_t)l15 * 64 + l4 * 8);
  bf16x8 qf1 = *(const bf16x8*)(Qp + (size_t)l15 * 64 + 32 + l4 * 8);

  int srow = t >> 3, sc8 = t & 7;
  int scs = sc8 ^ (srow & 7);  // pre-swizzled global source (LDS dest linear)
  int wbase = __builtin_amdgcn_readfirstlane(w * 1024);

  const __bf16* KpS = Kh + (size_t)bh * S_ * 64 + (size_t)srow * 64 + scs * 8;
  const __bf16* VpS = VhT + (size_t)bh * 64 * S_ + (size_t)srow * S_ + scs * 8;

  // ---- pass A: denominator; 16 iters x 128 keys, 3-deep ring, swapped ----
  float l_part = 0.f;

#define ASTAGE(buf, kt)                                                        \
  {                                                                            \
    g2l16(KpS + (size_t)(kt) * 8192, (char*)KVl[buf] + wbase);                 \
    g2l16(KpS + (size_t)(kt) * 8192 + 4096, (char*)KVl[buf] + 8192 + wbase);   \
  }

  ASTAGE(0, 0)
  ASTAGE(1, 1)
  asm volatile("s_waitcnt vmcnt(2)" ::: "memory");
  __builtin_amdgcn_s_barrier();
  __builtin_amdgcn_sched_barrier(0);

  {
    int ring = 0;
    for (int kt = 0; kt < 16; ++kt) {
      int cur = ring;
      int rp2 = (ring == 0) ? 2 : ring - 1;
      if (kt + 2 < 16) ASTAGE(rp2, kt + 2)
      __builtin_amdgcn_sched_barrier(0);

#pragma unroll
      for (int t8 = 0; t8 < 8; ++t8) {
        int kr = t8 * 16 + l15;
        bf16x8 kf0 = KVl[cur][kr * 8 + ((l4) ^ (kr & 7))];
        bf16x8 kf1 = KVl[cur][kr * 8 + ((4 + l4) ^ (kr & 7))];
        f32x4 a_ = {0.f, 0.f, 0.f, 0.f};
        a_ = __builtin_amdgcn_mfma_f32_16x16x32_bf16(kf0, qf0, a_, 0, 0, 0);  // swapped
        a_ = __builtin_amdgcn_mfma_f32_16x16x32_bf16(kf1, qf1, a_, 0, 0, 0);
#pragma unroll
        for (int r = 0; r < 4; ++r) l_part += exp2_hw(a_[r]);
      }

      if (kt < 14) {
        asm volatile("s_waitcnt vmcnt(2)" ::: "memory");
        __builtin_amdgcn_s_barrier();
        __builtin_amdgcn_sched_barrier(0);
      } else if (kt == 14) {
        asm volatile("s_waitcnt vmcnt(0)" ::: "memory");
        __builtin_amdgcn_s_barrier();
        __builtin_amdgcn_sched_barrier(0);
      }
      ring = (ring == 2) ? 0 : ring + 1;
    }
  }
#undef ASTAGE

  // lanes sharing q=l15: {l15, l15+16, l15+32, l15+48}
  float inv_l;
  {
    float l = l_part;
    l += __shfl_xor(l, 16);
    l += __shfl_xor(l, 32);
    inv_l = 1.0f / l;
  }

  // all waves done reading pass-A buffers before pass B overwrites them
  __builtin_amdgcn_s_barrier();
  __builtin_amdgcn_sched_barrier(0);

  // ---- pass B: atten (dwordx4) + ctx; 32 iters x 64 keys, 3-deep ring ----
  f32x4 ctx[4] = {};
  float* aRowT = atten + ((size_t)bh * S_ + q0 + l15) * S_;  // per-lane q row
  __bf16* PlW = (__bf16*)(Pl + w * 176);

#define BSTAGE(buf, kt)                                                        \
  {                                                                            \
    g2l16(KpS + (size_t)(kt) * 4096, (char*)KVl[buf] + wbase);                 \
    g2l16(VpS + (size_t)(kt) * 64, (char*)KVl[buf] + 8192 + wbase);            \
  }

  BSTAGE(0, 0)
  BSTAGE(1, 1)
  asm volatile("s_waitcnt vmcnt(2)" ::: "memory");
  __builtin_amdgcn_s_barrier();
  __builtin_amdgcn_sched_barrier(0);

  {
    int ring = 0;
    for (int kt = 0; kt < 32; ++kt) {
      int cur = ring;
      int rp2 = (ring == 0) ? 2 : ring - 1;
      if (kt + 2 < 32) BSTAGE(rp2, kt + 2)
      // pin: stage loads issue BEFORE the 4 atten stores -> vmcnt counting holds
      __builtin_amdgcn_sched_barrier(0);

      f32x4 sc[4];
#pragma unroll
      for (int t8 = 0; t8 < 4; ++t8) {
        int kr = t8 * 16 + l15;
        bf16x8 kf0 = KVl[cur][kr * 8 + ((l4) ^ (kr & 7))];
        bf16x8 kf1 = KVl[cur][kr * 8 + ((4 + l4) ^ (kr & 7))];
        f32x4 a_ = {0.f, 0.f, 0.f, 0.f};
        a_ = __builtin_amdgcn_mfma_f32_16x16x32_bf16(kf0, qf0, a_, 0, 0, 0);  // swapped
        a_ = __builtin_amdgcn_mfma_f32_16x16x32_bf16(kf1, qf1, a_, 0, 0, 0);
        sc[t8] = a_;
      }

      // p[q=l15][k = kt*64 + t8*16 + l4*4 + r] -> vectorized along k
#pragma unroll
      for (int t8 = 0; t8 < 4; ++t8) {
        f32x4 pv;
        bf16x4 pb;
#pragma unroll
        for (int r = 0; r < 4; ++r) {
          float p = exp2_hw(sc[t8][r]) * inv_l;
          pv[r] = p;
          pb[r] = (__bf16)p;
        }
        *(f32x4*)(aRowT + kt * 64 + t8 * 16 + l4 * 4) = pv;
        *(bf16x4*)(PlW + l15 * 88 + t8 * 16 + l4 * 4) = pb;
      }

#pragma unroll
      for (int kc = 0; kc < 2; ++kc) {
        bf16x8 pa = Pl[w * 176 + l15 * 11 + kc * 4 + l4];  // unchanged layout
#pragma unroll
        for (int dt = 0; dt < 4; ++dt) {
          int vr = dt * 16 + l15;
          bf16x8 vf = KVl[cur][512 + vr * 8 + ((kc * 4 + l4) ^ (vr & 7))];
          ctx[dt] = __builtin_amdgcn_mfma_f32_16x16x32_bf16(pa, vf, ctx[dt], 0, 0, 0);
        }
      }

      // loads-first order; 4 stores/iter. oldest->newest at wait:
      // kt=0:   L1(2), L2(2), St0(4)            -> force L1  : vmcnt(6)
      // steady: L(t+1)2, St(t-1)4, L(t+2)2, St(t)4 -> force L(t+1): vmcnt(10)
      // kt=30:  L31(2), St29(4), St30(4)        -> force L31 : vmcnt(8)
      if (kt == 0) {
        asm volatile("s_waitcnt vmcnt(6)" ::: "memory");
        __builtin_amdgcn_s_barrier();
        __builtin_amdgcn_sched_barrier(0);
      } else if (kt < 30) {
        asm volatile("s_waitcnt vmcnt(10)" ::: "memory");
        __builtin_amdgcn_s_barrier();
        __builtin_amdgcn_sched_barrier(0);
      } else if (kt == 30) {
        asm volatile("s_waitcnt vmcnt(8)" ::: "memory");
        __builtin_amdgcn_s_barrier();
        __builtin_amdgcn_sched_barrier(0);
      }
      ring = (ring == 2) ? 0 : ring + 1;
    }
  }
#undef BSTAGE

  // epilogue: ctx -> ctxb [B,S,H*64] bf16 (rows q=l4*4+r, cols d=dt*16+l15)
  int b = bh >> 4, h = bh & 15;
#pragma unroll
  for (int dt = 0; dt < 4; ++dt) {
#pragma unroll
    for (int r = 0; r < 4; ++r) {
      size_t row = (size_t)b * S_ + q0 + l4 * 4 + r;
      ctxb[row * D_ + h * 64 + dt * 16 + l15] = (__bf16)ctx[dt][r];
    }
  }
}

// ---------------- K3: output projection -> fp32 d_out (R8 verbatim) --------
__global__ __launch_bounds__(256, 3) void k_out(
    const __bf16* __restrict__ X, const __bf16* __restrict__ W,
    const float* __restrict__ bias, float* __restrict__ O)
{
  __shared__ bf16x8 As[3][512];
  __shared__ bf16x8 Bs[3][512];

  int o = (blockIdx.x % 32) * 8 + blockIdx.x / 32;  // bijective, 256 = 32*8
  int nb = o & 7, mb = o >> 3;

  int t = threadIdx.x, lane = t & 63, w = t >> 6;
  int l15 = lane & 15, l4 = lane >> 4;
  int wr = w >> 1, wc = w & 1;
  int m0 = mb * 128, n0 = nb * 128;

  int srow = t >> 2, sc = t & 3;
  int ldsoff = __builtin_amdgcn_readfirstlane(w * 1024);
  const __bf16* Xs = X + (size_t)(m0 + srow) * 1024 + sc * 8;
  const __bf16* Wsp = W + (size_t)(n0 + srow) * 1024 + sc * 8;

#define PSTAGE(buf, kt)                                                        \
  {                                                                            \
    _Pragma("unroll")                                                          \
    for (int i = 0; i < 2; ++i) {                                              \
      int lo = __builtin_amdgcn_readfirstlane(i * 4096 + ldsoff);              \
      g2l16(Xs + (size_t)i * 64 * 1024 + (kt) * 32, (char*)As[buf] + lo);      \
      g2l16(Wsp + (size_t)i * 64 * 1024 + (kt) * 32, (char*)Bs[buf] + lo);     \
    }                                                                          \
  }

  f32x4 acc[4][4] = {};

  PSTAGE(0, 0)
  PSTAGE(1, 1)
  asm volatile("s_waitcnt vmcnt(4)" ::: "memory");
  __builtin_amdgcn_s_barrier();
  __builtin_amdgcn_sched_barrier(0);

  int ring = 0;
  for (int kt = 0; kt < 32; ++kt) {
    int cur = ring;
    int rp2 = (ring == 0) ? 2 : ring - 1;
    if (kt + 2 < 32) PSTAGE(rp2, kt + 2)
    __builtin_amdgcn_sched_barrier(0);

    bf16x8 af[4], bfr[4];
#pragma unroll
    for (int i = 0; i < 4; ++i) af[i] = As[cur][(wr * 64 + i * 16 + l15) * 4 + l4];
#pragma unroll
    for (int j = 0; j < 4; ++j) bfr[j] = Bs[cur][(wc * 64 + j * 16 + l15) * 4 + l4];
#pragma unroll
    for (int i = 0; i < 4; ++i)
#pragma unroll
      for (int j = 0; j < 4; ++j)
        acc[i][j] = __builtin_amdgcn_mfma_f32_16x16x32_bf16(af[i], bfr[j], acc[i][j], 0, 0, 0);

    if (kt < 30) {
      asm volatile("s_waitcnt vmcnt(4)" ::: "memory");
      __builtin_amdgcn_s_barrier();
      __builtin_amdgcn_sched_barrier(0);
    } else if (kt == 30) {
      asm volatile("s_waitcnt vmcnt(0)" ::: "memory");
      __builtin_amdgcn_s_barrier();
      __builtin_amdgcn_sched_barrier(0);
    }
    ring = (ring == 2) ? 0 : ring + 1;
  }
#undef PSTAGE

#pragma unroll
  for (int j = 0; j < 4; ++j) {
    int col = n0 + wc * 64 + j * 16 + l15;
    float bv_ = bias[col];
#pragma unroll
    for (int i = 0; i < 4; ++i) {
#pragma unroll
      for (int r = 0; r < 4; ++r) {
        int row = m0 + wr * 64 + i * 16 + l4 * 4 + r;
        O[(size_t)row * 1024 + col] = acc[i][j][r] + bv_;
      }
    }
  }
}

// ---------------- launch ----------------
extern "C" void kernel_launch(void* const* d_in, const int* in_sizes, int n_in,
                              void* d_out, int out_size, void* d_ws, size_t ws_size,
                              hipStream_t stream)
{
  const float* q  = (const float*)d_in[0];
  const float* k  = (const float*)d_in[1];
  const float* v  = (const float*)d_in[2];
  const float* Wq = (const float*)d_in[3];
  const float* bq = (const float*)d_in[4];
  const float* Wk = (const float*)d_in[5];
  const float* bk = (const float*)d_in[6];
  const float* Wv = (const float*)d_in[7];
  const float* bv = (const float*)d_in[8];
  const float* Wo = (const float*)d_in[9];
  const float* bo = (const float*)d_in[10];

  const size_t NBSD = (size_t)B_ * S_ * D_;   // 4194304
  const size_t NDD  = (size_t)D_ * D_;        // 1048576

  float* out = (float*)d_out;
  float* atten = out + NBSD;

  if (ws_size < (4 * NDD + 4 * NBSD) * 2) return;  // ~41.9 MB needed

  __bf16* ws = (__bf16*)d_ws;
  __bf16* Wqb = ws;
  __bf16* Wkb = Wqb + NDD;
  __bf16* Wvb = Wkb + NDD;
  __bf16* Wob = Wvb + NDD;
  __bf16* Qh  = Wob + NDD;
  __bf16* Kh  = Qh + NBSD;
  __bf16* VhT = Kh + NBSD;
  __bf16* ctxb = VhT + NBSD;

  CvtArgs ca;
  ca.s[0] = Wq; ca.d[0] = Wqb;
  ca.s[1] = Wk; ca.d[1] = Wkb;
  ca.s[2] = Wv; ca.d[2] = Wvb;
  ca.s[3] = Wo; ca.d[3] = Wob;

  k_cvt<<<dim3(512, 4), 256, 0, stream>>>(ca);
  k_proj<<<dim3(768), 256, 0, stream>>>(q, k, v, Wqb, Wkb, Wvb,
                                        bq, bk, bv, Qh, Kh, VhT);
  k_attn<<<dim3(512), 512, 0, stream>>>(Qh, Kh, VhT, atten, ctxb);
  k_out<<<dim3(256), 256, 0, stream>>>(ctxb, Wob, bo, out);
}

// Round 11
// 246.274 us; speedup vs baseline: 1.1267x; 1.0091x over previous
//
#include <hip/hip_runtime.h>
#include <cstdint>

#define B_ 2
#define S_ 2048
#define D_ 1024
#define H_ 16

typedef __bf16 bf16x8 __attribute__((ext_vector_type(8)));
typedef __bf16 bf16x4 __attribute__((ext_vector_type(4)));
typedef float  f32x4  __attribute__((ext_vector_type(4)));

// async global->LDS, 16B per lane; LDS dest = wave-uniform base + lane*16 (HW)
__device__ __forceinline__ void g2l16(const void* g, void* l) {
  auto* gp = reinterpret_cast<const __attribute__((address_space(1))) uint32_t*>(
      reinterpret_cast<uintptr_t>(g));
  auto* lp = reinterpret_cast<__attribute__((address_space(3))) uint32_t*>(
      reinterpret_cast<uintptr_t>(l));
  __builtin_amdgcn_global_load_lds(gp, lp, 16, 0, 0);
}

__device__ __forceinline__ float exp2_hw(float x) {
#if __has_builtin(__builtin_amdgcn_exp2f)
  return __builtin_amdgcn_exp2f(x);
#else
  return __exp2f(x);
#endif
}

// ---------------- K0: fp32 -> bf16 conversion (WEIGHTS ONLY) ----------------
struct CvtArgs {
  const float* s[4];
  __bf16* d[4];
};

__global__ __launch_bounds__(256) void k_cvt(CvtArgs a) {
  int t = blockIdx.y;
  long base = ((long)blockIdx.x * blockDim.x + threadIdx.x) * 8;
  const float4* sp = (const float4*)(a.s[t] + base);
  float4 x = sp[0], y = sp[1];
  bf16x8 o;
  o[0] = (__bf16)x.x; o[1] = (__bf16)x.y; o[2] = (__bf16)x.z; o[3] = (__bf16)x.w;
  o[4] = (__bf16)y.x; o[5] = (__bf16)y.y; o[6] = (__bf16)y.z; o[7] = (__bf16)y.w;
  *(bf16x8*)(a.d[t] + base) = o;
}

// ---------------- K1: QKV projection GEMM, fp32 X input ---------------------
// XCD-clustered 1-D grid (R8). NEW: depth-2 A register staging — ALOAD(t+2)
// issued at top of iter t (two named register sets, manual unroll x2), so the
// fp32 X HBM load gets ~2 iterations of latency cover instead of ~1.
__global__ __launch_bounds__(256, 3) void k_proj(
    const float* __restrict__ Xq, const float* __restrict__ Xk, const float* __restrict__ Xv,
    const __bf16* __restrict__ Wq, const __bf16* __restrict__ Wk, const __bf16* __restrict__ Wv,
    const float* __restrict__ bq, const float* __restrict__ bk, const float* __restrict__ bv,
    __bf16* __restrict__ Oq, __bf16* __restrict__ Ok, __bf16* __restrict__ OvT)
{
  int o = (blockIdx.x % 96) * 8 + blockIdx.x / 96;  // bijective, 768 = 96*8
  int nb = o & 7, mb = (o >> 3) & 31, z = o >> 8;

  const float* X = (z == 0) ? Xq : (z == 1) ? Xk : Xv;
  const __bf16* W = (z == 0) ? Wq : (z == 1) ? Wk : Wv;
  const float* bias = (z == 0) ? bq : (z == 1) ? bk : bv;
  float scale = (z == 0) ? 0.180336880111183f : 1.0f;  // 0.125 * log2(e)

  __shared__ __align__(16) char smem[40960];  // As[2] 16K + Bs[3] 24K; Tt reuses
  bf16x8 (*As)[512] = (bf16x8(*)[512])smem;
  bf16x8 (*Bs)[512] = (bf16x8(*)[512])(smem + 16384);

  int t = threadIdx.x, lane = t & 63, w = t >> 6;
  int l15 = lane & 15, l4 = lane >> 4;
  int wr = w >> 1, wc = w & 1;
  int m0 = mb * 128, n0 = nb * 128;

  int arow = t >> 1, ac2 = (t & 1) * 2;
  const float* Xs = X + (size_t)(m0 + arow) * 1024 + (t & 1) * 16;
  int srow = t >> 2, sc = t & 3;
  const __bf16* Wsp = W + (size_t)(n0 + srow) * 1024 + sc * 8;
  int ldsoff = __builtin_amdgcn_readfirstlane(w * 1024);

  // two named A register sets (depth-2 staging, rule: static indexing only)
  float4 pa0, pa1, pa2, pa3;  // set 0: holds A(even kt)
  float4 pb0, pb1, pb2, pb3;  // set 1: holds A(odd kt)

#define ALOAD0(kt)                                                             \
  {                                                                            \
    const float4* ap = (const float4*)(Xs + (size_t)(kt) * 32);                \
    pa0 = ap[0]; pa1 = ap[1]; pa2 = ap[2]; pa3 = ap[3];                        \
  }
#define ALOAD1(kt)                                                             \
  {                                                                            \
    const float4* ap = (const float4*)(Xs + (size_t)(kt) * 32);                \
    pb0 = ap[0]; pb1 = ap[1]; pb2 = ap[2]; pb3 = ap[3];                        \
  }
#define AWRITE(buf, q0_, q1_, q2_, q3_)                                        \
  {                                                                            \
    bf16x8 lo, hi;                                                             \
    lo[0] = (__bf16)q0_.x; lo[1] = (__bf16)q0_.y; lo[2] = (__bf16)q0_.z;       \
    lo[3] = (__bf16)q0_.w; lo[4] = (__bf16)q1_.x; lo[5] = (__bf16)q1_.y;       \
    lo[6] = (__bf16)q1_.z; lo[7] = (__bf16)q1_.w;                              \
    hi[0] = (__bf16)q2_.x; hi[1] = (__bf16)q2_.y; hi[2] = (__bf16)q2_.z;       \
    hi[3] = (__bf16)q2_.w; hi[4] = (__bf16)q3_.x; hi[5] = (__bf16)q3_.y;       \
    hi[6] = (__bf16)q3_.z; hi[7] = (__bf16)q3_.w;                              \
    As[buf][arow * 4 + ac2] = lo;                                              \
    As[buf][arow * 4 + ac2 + 1] = hi;                                          \
  }
#define BSTG(buf, kt)                                                          \
  {                                                                            \
    _Pragma("unroll")                                                          \
    for (int i = 0; i < 2; ++i) {                                              \
      int lo_ = __builtin_amdgcn_readfirstlane(i * 4096 + ldsoff);             \
      g2l16(Wsp + (size_t)i * 64 * 1024 + (kt) * 32, (char*)Bs[buf] + lo_);    \
    }                                                                          \
  }

  f32x4 acc[4][4] = {};

  // prologue: B0(2), A0(4), B1(2), A1(4) -> vmcnt(6) forces B0+A0
  BSTG(0, 0)
  ALOAD0(0)
  BSTG(1, 1)
  ALOAD1(1)
  asm volatile("s_waitcnt vmcnt(6)" ::: "memory");
  AWRITE(0, pa0, pa1, pa2, pa3)
  asm volatile("s_waitcnt lgkmcnt(0)" ::: "memory");
  __builtin_amdgcn_s_barrier();
  __builtin_amdgcn_sched_barrier(0);

  // main loop, manually unrolled x2 so A-set selection is static.
  // Per iter t: issue BSTG(t+2)+ALOAD(t+2) at TOP; MFMA on As[t&1], Bs[bring];
  // wait vmcnt(6) [in-flight: B(t+1)2, A(t+1)4, B(t+2)2, A(t+2)4 -> forces
  // B(t+1)+A(t+1)]; AWRITE(t+1); barrier.
  int bring = 0;  // Bs index holding B(kt)
#define PITER(KT, LOADNXT, ASETCUR_IS_0)                                       \
  {                                                                            \
    int bcur = bring;                                                          \
    int bp2 = (bring >= 1) ? bring - 1 : 2;                                    \
    if ((KT) + 2 < 32) {                                                       \
      BSTG(bp2, (KT) + 2)                                                      \
      LOADNXT((KT) + 2)                                                        \
    }                                                                          \
    __builtin_amdgcn_sched_barrier(0);                                         \
    bf16x8 af[4], bfr[4];                                                      \
    _Pragma("unroll")                                                          \
    for (int i = 0; i < 4; ++i)                                                \
      af[i] = As[(KT) & 1][(wr * 64 + i * 16 + l15) * 4 + l4];                 \
    _Pragma("unroll")                                                          \
    for (int j = 0; j < 4; ++j)                                                \
      bfr[j] = Bs[bcur][(wc * 64 + j * 16 + l15) * 4 + l4];                    \
    _Pragma("unroll")                                                          \
    for (int i = 0; i < 4; ++i)                                                \
      _Pragma("unroll")                                                        \
      for (int j = 0; j < 4; ++j)                                              \
        acc[i][j] =                                                            \
            __builtin_amdgcn_mfma_f32_16x16x32_bf16(af[i], bfr[j], acc[i][j],  \
                                                    0, 0, 0);                  \
    __builtin_amdgcn_sched_barrier(0);                                         \
    if ((KT) + 1 < 32) {                                                       \
      if ((KT) + 2 < 32) {                                                     \
        asm volatile("s_waitcnt vmcnt(6)" ::: "memory");                       \
      } else {                                                                 \
        asm volatile("s_waitcnt vmcnt(0)" ::: "memory");                       \
      }                                                                        \
      if (ASETCUR_IS_0) {                                                      \
        AWRITE(((KT) + 1) & 1, pb0, pb1, pb2, pb3)                             \
      } else {                                                                 \
        AWRITE(((KT) + 1) & 1, pa0, pa1, pa2, pa3)                             \
      }                                                                        \
      asm volatile("s_waitcnt lgkmcnt(0)" ::: "memory");                       \
      __builtin_amdgcn_s_barrier();                                            \
      __builtin_amdgcn_sched_barrier(0);                                       \
    }                                                                          \
    bring = (bring == 2) ? 0 : bring + 1;                                      \
  }

  for (int kt = 0; kt < 32; kt += 2) {
    PITER(kt, ALOAD0, 1)       // even kt: A(kt) in set0/As[0]; A(kt+2)->set0
    PITER(kt + 1, ALOAD1, 0)   // odd kt:  A(kt) in set1/As[1]; A(kt+2)->set1
  }
#undef PITER
#undef ALOAD0
#undef ALOAD1
#undef AWRITE
#undef BSTG

  if (z == 2) {
    __syncthreads();
    __bf16* Tt = (__bf16*)smem;
    const int LDT = 136;
    int b = m0 >> 11, ss0 = m0 & 2047;
#pragma unroll
    for (int p = 0; p < 2; ++p) {
      if (wc == p) {
#pragma unroll
        for (int j = 0; j < 4; ++j) {
          float bv_ = bias[n0 + p * 64 + j * 16 + l15];
#pragma unroll
          for (int i = 0; i < 4; ++i) {
            bf16x4 pv;
#pragma unroll
            for (int r = 0; r < 4; ++r) pv[r] = (__bf16)(acc[i][j][r] + bv_);
            *(bf16x4*)&Tt[(j * 16 + l15) * LDT + wr * 64 + i * 16 + l4 * 4] = pv;
          }
        }
      }
      __syncthreads();
      int h = (n0 >> 6) + p;
      __bf16* dst = OvT + ((size_t)(b * H_ + h) * 64) * S_ + ss0;
#pragma unroll
      for (int it = 0; it < 4; ++it) {
        int nl = it * 16 + (t >> 4);
        int mc = (t & 15) * 8;
        bf16x8 vv = *(bf16x8*)&Tt[nl * LDT + mc];
        *(bf16x8*)(dst + (size_t)nl * S_ + mc) = vv;
      }
      __syncthreads();
    }
  } else {
    __bf16* O = (z == 0) ? Oq : Ok;
#pragma unroll
    for (int j = 0; j < 4; ++j) {
      int col = n0 + wc * 64 + j * 16 + l15;
      float bv_ = bias[col];
      int h = col >> 6, hd = col & 63;
#pragma unroll
      for (int i = 0; i < 4; ++i) {
#pragma unroll
        for (int r = 0; r < 4; ++r) {
          int row = m0 + wr * 64 + i * 16 + l4 * 4 + r;
          int b = row >> 11, ss = row & 2047;
          float val = (acc[i][j][r] + bv_) * scale;
          O[(((size_t)b * H_ + h) * S_ + ss) * 64 + hd] = (__bf16)val;
        }
      }
    }
  }
}

// ---------------- K2: attention, two-sweep, no-max softmax (R8 verbatim) ----
__global__ __launch_bounds__(512, 4) void k_attn(
    const __bf16* __restrict__ Qh, const __bf16* __restrict__ Kh,
    const __bf16* __restrict__ VhT, float* __restrict__ atten,
    __bf16* __restrict__ ctxb)
{
  __shared__ bf16x8 KVl[3][1024];  // 3 x 16KB stages (A: 128 keys; B: 64K + 64V)
  __shared__ bf16x8 Pl[8 * 176];   // per-wave p: [16 rows][11 chunks]

  int bid = blockIdx.x;
  int sb = (bid & 7) * 64 + (bid >> 3);  // XCD swizzle (512 = 8*64, bijective)
  int bh = sb >> 4, qt = sb & 15;
  int t = threadIdx.x, lane = t & 63, w = t >> 6;
  int l15 = lane & 15, l4 = lane >> 4;
  int q0 = qt * 128 + w * 16;

  const __bf16* Qp = Qh + ((size_t)bh * S_ + q0) * 64;
  bf16x8 qf0 = *(const bf16x8*)(Qp + (size_t)l15 * 64 + l4 * 8);
  bf16x8 qf1 = *(const bf16x8*)(Qp + (size_t)l15 * 64 + 32 + l4 * 8);

  int srow = t >> 3, sc8 = t & 7;
  int scs = sc8 ^ (srow & 7);  // pre-swizzled global source (LDS dest linear)
  int wbase = __builtin_amdgcn_readfirstlane(w * 1024);

  const __bf16* KpS = Kh + (size_t)bh * S_ * 64 + (size_t)srow * 64 + scs * 8;
  const __bf16* VpS = VhT + (size_t)bh * 64 * S_ + (size_t)srow * S_ + scs * 8;

  // ---- pass A: softmax denominator; 16 iters x 128 keys, 3-deep ----
  float l_part[4] = {0.f, 0.f, 0.f, 0.f};

#define ASTAGE(buf, kt)                                                        \
  {                                                                            \
    g2l16(KpS + (size_t)(kt) * 8192, (char*)KVl[buf] + wbase);                 \
    g2l16(KpS + (size_t)(kt) * 8192 + 4096, (char*)KVl[buf] + 8192 + wbase);   \
  }

  ASTAGE(0, 0)
  ASTAGE(1, 1)
  asm volatile("s_waitcnt vmcnt(2)" ::: "memory");
  __builtin_amdgcn_s_barrier();
  __builtin_amdgcn_sched_barrier(0);

  {
    int ring = 0;
    for (int kt = 0; kt < 16; ++kt) {
      int cur = ring;
      int rp2 = (ring == 0) ? 2 : ring - 1;
      if (kt + 2 < 16) ASTAGE(rp2, kt + 2)
      __builtin_amdgcn_sched_barrier(0);

#pragma unroll
      for (int t8 = 0; t8 < 8; ++t8) {
        int kr = t8 * 16 + l15;
        bf16x8 kf0 = KVl[cur][kr * 8 + ((l4) ^ (kr & 7))];
        bf16x8 kf1 = KVl[cur][kr * 8 + ((4 + l4) ^ (kr & 7))];
        f32x4 a_ = {0.f, 0.f, 0.f, 0.f};
        a_ = __builtin_amdgcn_mfma_f32_16x16x32_bf16(qf0, kf0, a_, 0, 0, 0);
        a_ = __builtin_amdgcn_mfma_f32_16x16x32_bf16(qf1, kf1, a_, 0, 0, 0);
#pragma unroll
        for (int r = 0; r < 4; ++r) l_part[r] += exp2_hw(a_[r]);
      }

      if (kt < 14) {
        asm volatile("s_waitcnt vmcnt(2)" ::: "memory");
        __builtin_amdgcn_s_barrier();
        __builtin_amdgcn_sched_barrier(0);
      } else if (kt == 14) {
        asm volatile("s_waitcnt vmcnt(0)" ::: "memory");
        __builtin_amdgcn_s_barrier();
        __builtin_amdgcn_sched_barrier(0);
      }
      ring = (ring == 2) ? 0 : ring + 1;
    }
  }
#undef ASTAGE

  float inv_l[4];
#pragma unroll
  for (int r = 0; r < 4; ++r) {
    float l = l_part[r];
    l += __shfl_xor(l, 1);
    l += __shfl_xor(l, 2);
    l += __shfl_xor(l, 4);
    l += __shfl_xor(l, 8);
    inv_l[r] = 1.0f / l;
  }

  // all waves done reading pass-A buffers before pass B overwrites them
  __builtin_amdgcn_s_barrier();
  __builtin_amdgcn_sched_barrier(0);

  // ---- pass B: write atten + accumulate ctx; 32 iters x 64 keys ----
  f32x4 ctx[4] = {};
  float* aRow = atten + ((size_t)bh * S_ + q0) * S_;
  __bf16* PlW = (__bf16*)(Pl + w * 176);

#define BSTAGE(buf, kt)                                                        \
  {                                                                            \
    g2l16(KpS + (size_t)(kt) * 4096, (char*)KVl[buf] + wbase);                 \
    g2l16(VpS + (size_t)(kt) * 64, (char*)KVl[buf] + 8192 + wbase);            \
  }

  BSTAGE(0, 0)
  BSTAGE(1, 1)
  asm volatile("s_waitcnt vmcnt(2)" ::: "memory");
  __builtin_amdgcn_s_barrier();
  __builtin_amdgcn_sched_barrier(0);

  {
    int ring = 0;
    for (int kt = 0; kt < 32; ++kt) {
      int cur = ring;
      int rp2 = (ring == 0) ? 2 : ring - 1;
      if (kt + 2 < 32) BSTAGE(rp2, kt + 2)
      // pin: stage loads issue BEFORE the 16 atten stores, so vmcnt counting holds
      __builtin_amdgcn_sched_barrier(0);

      f32x4 sc[4];
#pragma unroll
      for (int t8 = 0; t8 < 4; ++t8) {
        int kr = t8 * 16 + l15;
        bf16x8 kf0 = KVl[cur][kr * 8 + ((l4) ^ (kr & 7))];
        bf16x8 kf1 = KVl[cur][kr * 8 + ((4 + l4) ^ (kr & 7))];
        f32x4 a_ = {0.f, 0.f, 0.f, 0.f};
        a_ = __builtin_amdgcn_mfma_f32_16x16x32_bf16(qf0, kf0, a_, 0, 0, 0);
        a_ = __builtin_amdgcn_mfma_f32_16x16x32_bf16(qf1, kf1, a_, 0, 0, 0);
        sc[t8] = a_;
      }

#pragma unroll
      for (int t8 = 0; t8 < 4; ++t8) {
#pragma unroll
        for (int r = 0; r < 4; ++r) {
          float p = exp2_hw(sc[t8][r]) * inv_l[r];
          aRow[(size_t)(l4 * 4 + r) * S_ + kt * 64 + t8 * 16 + l15] = p;
          PlW[(l4 * 4 + r) * 88 + t8 * 16 + l15] = (__bf16)p;
        }
      }

#pragma unroll
      for (int kc = 0; kc < 2; ++kc) {
        bf16x8 pa = Pl[w * 176 + l15 * 11 + kc * 4 + l4];
#pragma unroll
        for (int dt = 0; dt < 4; ++dt) {
          int vr = dt * 16 + l15;
          bf16x8 vf = KVl[cur][512 + vr * 8 + ((kc * 4 + l4) ^ (vr & 7))];
          ctx[dt] = __builtin_amdgcn_mfma_f32_16x16x32_bf16(pa, vf, ctx[dt], 0, 0, 0);
        }
      }

      if (kt < 31) {
        // steady state: newest-18 = L(t+2)2 + St(t)16 -> forces L(t+1) landed
        asm volatile("s_waitcnt vmcnt(18)" ::: "memory");
        __builtin_amdgcn_s_barrier();
        __builtin_amdgcn_sched_barrier(0);
      }
      ring = (ring == 2) ? 0 : ring + 1;
    }
  }
#undef BSTAGE

  int b = bh >> 4, h = bh & 15;
#pragma unroll
  for (int dt = 0; dt < 4; ++dt) {
#pragma unroll
    for (int r = 0; r < 4; ++r) {
      size_t row = (size_t)b * S_ + q0 + l4 * 4 + r;
      ctxb[row * D_ + h * 64 + dt * 16 + l15] = (__bf16)ctx[dt][r];
    }
  }
}

// ---------------- K3: output projection -> fp32 d_out (R8 verbatim) --------
__global__ __launch_bounds__(256, 3) void k_out(
    const __bf16* __restrict__ X, const __bf16* __restrict__ W,
    const float* __restrict__ bias, float* __restrict__ O)
{
  __shared__ bf16x8 As[3][512];
  __shared__ bf16x8 Bs[3][512];

  int o = (blockIdx.x % 32) * 8 + blockIdx.x / 32;  // bijective, 256 = 32*8
  int nb = o & 7, mb = o >> 3;

  int t = threadIdx.x, lane = t & 63, w = t >> 6;
  int l15 = lane & 15, l4 = lane >> 4;
  int wr = w >> 1, wc = w & 1;
  int m0 = mb * 128, n0 = nb * 128;

  int srow = t >> 2, sc = t & 3;
  int ldsoff = __builtin_amdgcn_readfirstlane(w * 1024);
  const __bf16* Xs = X + (size_t)(m0 + srow) * 1024 + sc * 8;
  const __bf16* Wsp = W + (size_t)(n0 + srow) * 1024 + sc * 8;

#define PSTAGE(buf, kt)                                                        \
  {                                                                            \
    _Pragma("unroll")                                                          \
    for (int i = 0; i < 2; ++i) {                                              \
      int lo = __builtin_amdgcn_readfirstlane(i * 4096 + ldsoff);              \
      g2l16(Xs + (size_t)i * 64 * 1024 + (kt) * 32, (char*)As[buf] + lo);      \
      g2l16(Wsp + (size_t)i * 64 * 1024 + (kt) * 32, (char*)Bs[buf] + lo);     \
    }                                                                          \
  }

  f32x4 acc[4][4] = {};

  PSTAGE(0, 0)
  PSTAGE(1, 1)
  asm volatile("s_waitcnt vmcnt(4)" ::: "memory");
  __builtin_amdgcn_s_barrier();
  __builtin_amdgcn_sched_barrier(0);

  int ring = 0;
  for (int kt = 0; kt < 32; ++kt) {
    int cur = ring;
    int rp2 = (ring == 0) ? 2 : ring - 1;
    if (kt + 2 < 32) PSTAGE(rp2, kt + 2)
    __builtin_amdgcn_sched_barrier(0);

    bf16x8 af[4], bfr[4];
#pragma unroll
    for (int i = 0; i < 4; ++i) af[i] = As[cur][(wr * 64 + i * 16 + l15) * 4 + l4];
#pragma unroll
    for (int j = 0; j < 4; ++j) bfr[j] = Bs[cur][(wc * 64 + j * 16 + l15) * 4 + l4];
#pragma unroll
    for (int i = 0; i < 4; ++i)
#pragma unroll
      for (int j = 0; j < 4; ++j)
        acc[i][j] = __builtin_amdgcn_mfma_f32_16x16x32_bf16(af[i], bfr[j], acc[i][j], 0, 0, 0);

    if (kt < 30) {
      asm volatile("s_waitcnt vmcnt(4)" ::: "memory");
      __builtin_amdgcn_s_barrier();
      __builtin_amdgcn_sched_barrier(0);
    } else if (kt == 30) {
      asm volatile("s_waitcnt vmcnt(0)" ::: "memory");
      __builtin_amdgcn_s_barrier();
      __builtin_amdgcn_sched_barrier(0);
    }
    ring = (ring == 2) ? 0 : ring + 1;
  }
#undef PSTAGE

#pragma unroll
  for (int j = 0; j < 4; ++j) {
    int col = n0 + wc * 64 + j * 16 + l15;
    float bv_ = bias[col];
#pragma unroll
    for (int i = 0; i < 4; ++i) {
#pragma unroll
      for (int r = 0; r < 4; ++r) {
        int row = m0 + wr * 64 + i * 16 + l4 * 4 + r;
        O[(size_t)row * 1024 + col] = acc[i][j][r] + bv_;
      }
    }
  }
}

// ---------------- launch ----------------
extern "C" void kernel_launch(void* const* d_in, const int* in_sizes, int n_in,
                              void* d_out, int out_size, void* d_ws, size_t ws_size,
                              hipStream_t stream)
{
  const float* q  = (const float*)d_in[0];
  const float* k  = (const float*)d_in[1];
  const float* v  = (const float*)d_in[2];
  const float* Wq = (const float*)d_in[3];
  const float* bq = (const float*)d_in[4];
  const float* Wk = (const float*)d_in[5];
  const float* bk = (const float*)d_in[6];
  const float* Wv = (const float*)d_in[7];
  const float* bv = (const float*)d_in[8];
  const float* Wo = (const float*)d_in[9];
  const float* bo = (const float*)d_in[10];

  const size_t NBSD = (size_t)B_ * S_ * D_;   // 4194304
  const size_t NDD  = (size_t)D_ * D_;        // 1048576

  float* out = (float*)d_out;
  float* atten = out + NBSD;

  if (ws_size < (4 * NDD + 4 * NBSD) * 2) return;  // ~41.9 MB needed

  __bf16* ws = (__bf16*)d_ws;
  __bf16* Wqb = ws;
  __bf16* Wkb = Wqb + NDD;
  __bf16* Wvb = Wkb + NDD;
  __bf16* Wob = Wvb + NDD;
  __bf16* Qh  = Wob + NDD;
  __bf16* Kh  = Qh + NBSD;
  __bf16* VhT = Kh + NBSD;
  __bf16* ctxb = VhT + NBSD;

  CvtArgs ca;
  ca.s[0] = Wq; ca.d[0] = Wqb;
  ca.s[1] = Wk; ca.d[1] = Wkb;
  ca.s[2] = Wv; ca.d[2] = Wvb;
  ca.s[3] = Wo; ca.d[3] = Wob;

  k_cvt<<<dim3(512, 4), 256, 0, stream>>>(ca);
  k_proj<<<dim3(768), 256, 0, stream>>>(q, k, v, Wqb, Wkb, Wvb,
                                        bq, bk, bv, Qh, Kh, VhT);
  k_attn<<<dim3(512), 512, 0, stream>>>(Qh, Kh, VhT, atten, ctxb);
  k_out<<<dim3(256), 256, 0, stream>>>(ctxb, Wob, bo, out);
}

// Round 12
// 237.972 us; speedup vs baseline: 1.1660x; 1.0349x over previous
//
#include <hip/hip_runtime.h>
#include <cstdint>

#define B_ 2
#define S_ 2048
#define D_ 1024
#define H_ 16

typedef __bf16 bf16x8 __attribute__((ext_vector_type(8)));
typedef __bf16 bf16x4 __attribute__((ext_vector_type(4)));
typedef float  f32x4  __attribute__((ext_vector_type(4)));

// async global->LDS, 16B per lane; LDS dest = wave-uniform base + lane*16 (HW)
__device__ __forceinline__ void g2l16(const void* g, void* l) {
  auto* gp = reinterpret_cast<const __attribute__((address_space(1))) uint32_t*>(
      reinterpret_cast<uintptr_t>(g));
  auto* lp = reinterpret_cast<__attribute__((address_space(3))) uint32_t*>(
      reinterpret_cast<uintptr_t>(l));
  __builtin_amdgcn_global_load_lds(gp, lp, 16, 0, 0);
}

__device__ __forceinline__ float exp2_hw(float x) {
#if __has_builtin(__builtin_amdgcn_exp2f)
  return __builtin_amdgcn_exp2f(x);
#else
  return __exp2f(x);
#endif
}

// ---------------- K0: fp32 -> bf16 conversion (WEIGHTS ONLY) ----------------
struct CvtArgs {
  const float* s[4];
  __bf16* d[4];
};

__global__ __launch_bounds__(256) void k_cvt(CvtArgs a) {
  int t = blockIdx.y;
  long base = ((long)blockIdx.x * blockDim.x + threadIdx.x) * 8;
  const float4* sp = (const float4*)(a.s[t] + base);
  float4 x = sp[0], y = sp[1];
  bf16x8 o;
  o[0] = (__bf16)x.x; o[1] = (__bf16)x.y; o[2] = (__bf16)x.z; o[3] = (__bf16)x.w;
  o[4] = (__bf16)y.x; o[5] = (__bf16)y.y; o[6] = (__bf16)y.z; o[7] = (__bf16)y.w;
  *(bf16x8*)(a.d[t] + base) = o;
}

// ---------------- K1: QKV projection GEMM, fp32 X input ---------------------
// 1-D grid 768, XCD-clustered remap: the 8 n-blocks sharing an X panel land on
// the SAME XCD (bid%8 == group%8), co-resident -> X panel fetched once per L2.
__global__ __launch_bounds__(256, 3) void k_proj(
    const float* __restrict__ Xq, const float* __restrict__ Xk, const float* __restrict__ Xv,
    const __bf16* __restrict__ Wq, const __bf16* __restrict__ Wk, const __bf16* __restrict__ Wv,
    const float* __restrict__ bq, const float* __restrict__ bk, const float* __restrict__ bv,
    __bf16* __restrict__ Oq, __bf16* __restrict__ Ok, __bf16* __restrict__ OvT)
{
  int o = (blockIdx.x % 96) * 8 + blockIdx.x / 96;  // bijective, 768 = 96*8
  int nb = o & 7, mb = (o >> 3) & 31, z = o >> 8;

  const float* X = (z == 0) ? Xq : (z == 1) ? Xk : Xv;
  const __bf16* W = (z == 0) ? Wq : (z == 1) ? Wk : Wv;
  const float* bias = (z == 0) ? bq : (z == 1) ? bk : bv;
  float scale = (z == 0) ? 0.180336880111183f : 1.0f;  // 0.125 * log2(e)

  __shared__ __align__(16) char smem[40960];
  bf16x8 (*As)[512] = (bf16x8(*)[512])smem;
  bf16x8 (*Bs)[512] = (bf16x8(*)[512])(smem + 16384);

  int t = threadIdx.x, lane = t & 63, w = t >> 6;
  int l15 = lane & 15, l4 = lane >> 4;
  int wr = w >> 1, wc = w & 1;
  int m0 = mb * 128, n0 = nb * 128;

  int arow = t >> 1, ac2 = (t & 1) * 2;
  const float* Xs = X + (size_t)(m0 + arow) * 1024 + (t & 1) * 16;
  int srow = t >> 2, sc = t & 3;
  const __bf16* Wsp = W + (size_t)(n0 + srow) * 1024 + sc * 8;
  int ldsoff = __builtin_amdgcn_readfirstlane(w * 1024);

  float4 a0, a1, a2, a3;

#define ALOAD(kt)                                                              \
  {                                                                            \
    const float4* ap = (const float4*)(Xs + (size_t)(kt) * 32);                \
    a0 = ap[0]; a1 = ap[1]; a2 = ap[2]; a3 = ap[3];                            \
  }
#define AWRITE(buf)                                                            \
  {                                                                            \
    bf16x8 lo, hi;                                                             \
    lo[0] = (__bf16)a0.x; lo[1] = (__bf16)a0.y; lo[2] = (__bf16)a0.z;          \
    lo[3] = (__bf16)a0.w; lo[4] = (__bf16)a1.x; lo[5] = (__bf16)a1.y;          \
    lo[6] = (__bf16)a1.z; lo[7] = (__bf16)a1.w;                                \
    hi[0] = (__bf16)a2.x; hi[1] = (__bf16)a2.y; hi[2] = (__bf16)a2.z;          \
    hi[3] = (__bf16)a2.w; hi[4] = (__bf16)a3.x; hi[5] = (__bf16)a3.y;          \
    hi[6] = (__bf16)a3.z; hi[7] = (__bf16)a3.w;                                \
    As[buf][arow * 4 + ac2] = lo;                                              \
    As[buf][arow * 4 + ac2 + 1] = hi;                                          \
  }
#define BSTG(buf, kt)                                                          \
  {                                                                            \
    _Pragma("unroll")                                                          \
    for (int i = 0; i < 2; ++i) {                                              \
      int lo_ = __builtin_amdgcn_readfirstlane(i * 4096 + ldsoff);             \
      g2l16(Wsp + (size_t)i * 64 * 1024 + (kt) * 32, (char*)Bs[buf] + lo_);    \
    }                                                                          \
  }

  f32x4 acc[4][4] = {};

  BSTG(0, 0)
  ALOAD(0)
  BSTG(1, 1)
  asm volatile("s_waitcnt vmcnt(2)" ::: "memory");
  AWRITE(0)
  ALOAD(1)
  asm volatile("s_waitcnt lgkmcnt(0)" ::: "memory");
  __builtin_amdgcn_s_barrier();
  __builtin_amdgcn_sched_barrier(0);

  int bring = 0;
  for (int kt = 0; kt < 32; ++kt) {
    int bcur = bring;
    int bp2 = (bring >= 1) ? bring - 1 : 2;
    int acur = kt & 1, anxt = acur ^ 1;
    if (kt + 2 < 32) BSTG(bp2, kt + 2)
    __builtin_amdgcn_sched_barrier(0);

    bf16x8 af[4], bfr[4];
#pragma unroll
    for (int i = 0; i < 4; ++i) af[i] = As[acur][(wr * 64 + i * 16 + l15) * 4 + l4];
#pragma unroll
    for (int j = 0; j < 4; ++j) bfr[j] = Bs[bcur][(wc * 64 + j * 16 + l15) * 4 + l4];
#pragma unroll
    for (int i = 0; i < 4; ++i)
#pragma unroll
      for (int j = 0; j < 4; ++j)
        acc[i][j] = __builtin_amdgcn_mfma_f32_16x16x32_bf16(af[i], bfr[j], acc[i][j], 0, 0, 0);
    __builtin_amdgcn_sched_barrier(0);

    if (kt + 1 < 32) {
      if (kt + 2 < 32) {
        asm volatile("s_waitcnt vmcnt(2)" ::: "memory");
      } else {
        asm volatile("s_waitcnt vmcnt(0)" ::: "memory");
      }
      AWRITE(anxt)
      if (kt + 2 < 32) ALOAD(kt + 2)
      asm volatile("s_waitcnt lgkmcnt(0)" ::: "memory");
      __builtin_amdgcn_s_barrier();
      __builtin_amdgcn_sched_barrier(0);
    }
    bring = (bring == 2) ? 0 : bring + 1;
  }
#undef ALOAD
#undef AWRITE
#undef BSTG

  if (z == 2) {
    __syncthreads();
    __bf16* Tt = (__bf16*)smem;
    const int LDT = 136;
    int b = m0 >> 11, ss0 = m0 & 2047;
#pragma unroll
    for (int p = 0; p < 2; ++p) {
      if (wc == p) {
#pragma unroll
        for (int j = 0; j < 4; ++j) {
          float bv_ = bias[n0 + p * 64 + j * 16 + l15];
#pragma unroll
          for (int i = 0; i < 4; ++i) {
            bf16x4 pv;
#pragma unroll
            for (int r = 0; r < 4; ++r) pv[r] = (__bf16)(acc[i][j][r] + bv_);
            *(bf16x4*)&Tt[(j * 16 + l15) * LDT + wr * 64 + i * 16 + l4 * 4] = pv;
          }
        }
      }
      __syncthreads();
      int h = (n0 >> 6) + p;
      __bf16* dst = OvT + ((size_t)(b * H_ + h) * 64) * S_ + ss0;
#pragma unroll
      for (int it = 0; it < 4; ++it) {
        int nl = it * 16 + (t >> 4);
        int mc = (t & 15) * 8;
        bf16x8 vv = *(bf16x8*)&Tt[nl * LDT + mc];
        *(bf16x8*)(dst + (size_t)nl * S_ + mc) = vv;
      }
      __syncthreads();
    }
  } else {
    __bf16* O = (z == 0) ? Oq : Ok;
#pragma unroll
    for (int j = 0; j < 4; ++j) {
      int col = n0 + wc * 64 + j * 16 + l15;
      float bv_ = bias[col];
      int h = col >> 6, hd = col & 63;
#pragma unroll
      for (int i = 0; i < 4; ++i) {
#pragma unroll
        for (int r = 0; r < 4; ++r) {
          int row = m0 + wr * 64 + i * 16 + l4 * 4 + r;
          int b = row >> 11, ss = row & 2047;
          float val = (acc[i][j][r] + bv_) * scale;
          O[(((size_t)b * H_ + h) * S_ + ss) * 64 + hd] = (__bf16)val;
        }
      }
    }
  }
}

// ---------------- K2: attention, two-sweep, no-max softmax ----------------
__global__ __launch_bounds__(512, 4) void k_attn(
    const __bf16* __restrict__ Qh, const __bf16* __restrict__ Kh,
    const __bf16* __restrict__ VhT, float* __restrict__ atten,
    __bf16* __restrict__ ctxb)
{
  __shared__ bf16x8 KVl[3][1024];  // 3 x 16KB stages (A: 128 keys; B: 64K + 64V)
  __shared__ bf16x8 Pl[8 * 176];   // per-wave p: [16 rows][11 chunks]

  int bid = blockIdx.x;
  int sb = (bid & 7) * 64 + (bid >> 3);  // XCD swizzle (512 = 8*64, bijective)
  int bh = sb >> 4, qt = sb & 15;
  int t = threadIdx.x, lane = t & 63, w = t >> 6;
  int l15 = lane & 15, l4 = lane >> 4;
  int q0 = qt * 128 + w * 16;

  const __bf16* Qp = Qh + ((size_t)bh * S_ + q0) * 64;
  bf16x8 qf0 = *(const bf16x8*)(Qp + (size_t)l15 * 64 + l4 * 8);
  bf16x8 qf1 = *(const bf16x8*)(Qp + (size_t)l15 * 64 + 32 + l4 * 8);

  int srow = t >> 3, sc8 = t & 7;
  int scs = sc8 ^ (srow & 7);  // pre-swizzled global source (LDS dest linear)
  int wbase = __builtin_amdgcn_readfirstlane(w * 1024);

  const __bf16* KpS = Kh + (size_t)bh * S_ * 64 + (size_t)srow * 64 + scs * 8;
  const __bf16* VpS = VhT + (size_t)bh * 64 * S_ + (size_t)srow * S_ + scs * 8;

  // ---- pass A: softmax denominator; 16 iters x 128 keys, 3-deep ----
  float l_part[4] = {0.f, 0.f, 0.f, 0.f};

#define ASTAGE(buf, kt)                                                        \
  {                                                                            \
    g2l16(KpS + (size_t)(kt) * 8192, (char*)KVl[buf] + wbase);                 \
    g2l16(KpS + (size_t)(kt) * 8192 + 4096, (char*)KVl[buf] + 8192 + wbase);   \
  }

  ASTAGE(0, 0)
  ASTAGE(1, 1)
  asm volatile("s_waitcnt vmcnt(2)" ::: "memory");
  __builtin_amdgcn_s_barrier();
  __builtin_amdgcn_sched_barrier(0);

  {
    int ring = 0;
    for (int kt = 0; kt < 16; ++kt) {
      int cur = ring;
      int rp2 = (ring == 0) ? 2 : ring - 1;
      if (kt + 2 < 16) ASTAGE(rp2, kt + 2)
      __builtin_amdgcn_sched_barrier(0);

#pragma unroll
      for (int t8 = 0; t8 < 8; ++t8) {
        int kr = t8 * 16 + l15;
        bf16x8 kf0 = KVl[cur][kr * 8 + ((l4) ^ (kr & 7))];
        bf16x8 kf1 = KVl[cur][kr * 8 + ((4 + l4) ^ (kr & 7))];
        f32x4 a_ = {0.f, 0.f, 0.f, 0.f};
        a_ = __builtin_amdgcn_mfma_f32_16x16x32_bf16(qf0, kf0, a_, 0, 0, 0);
        a_ = __builtin_amdgcn_mfma_f32_16x16x32_bf16(qf1, kf1, a_, 0, 0, 0);
#pragma unroll
        for (int r = 0; r < 4; ++r) l_part[r] += exp2_hw(a_[r]);
      }

      if (kt < 14) {
        asm volatile("s_waitcnt vmcnt(2)" ::: "memory");
        __builtin_amdgcn_s_barrier();
        __builtin_amdgcn_sched_barrier(0);
      } else if (kt == 14) {
        asm volatile("s_waitcnt vmcnt(0)" ::: "memory");
        __builtin_amdgcn_s_barrier();
        __builtin_amdgcn_sched_barrier(0);
      }
      ring = (ring == 2) ? 0 : ring + 1;
    }
  }
#undef ASTAGE

  float inv_l[4];
#pragma unroll
  for (int r = 0; r < 4; ++r) {
    float l = l_part[r];
    l += __shfl_xor(l, 1);
    l += __shfl_xor(l, 2);
    l += __shfl_xor(l, 4);
    l += __shfl_xor(l, 8);
    inv_l[r] = 1.0f / l;
  }

  // all waves done reading pass-A buffers before pass B overwrites them
  __builtin_amdgcn_s_barrier();
  __builtin_amdgcn_sched_barrier(0);

  // ---- pass B: write atten + accumulate ctx; 32 iters x 64 keys ----
  f32x4 ctx[4] = {};
  float* aRow = atten + ((size_t)bh * S_ + q0) * S_;
  __bf16* PlW = (__bf16*)(Pl + w * 176);

#define BSTAGE(buf, kt)                                                        \
  {                                                                            \
    g2l16(KpS + (size_t)(kt) * 4096, (char*)KVl[buf] + wbase);                 \
    g2l16(VpS + (size_t)(kt) * 64, (char*)KVl[buf] + 8192 + wbase);            \
  }

  BSTAGE(0, 0)
  BSTAGE(1, 1)
  asm volatile("s_waitcnt vmcnt(2)" ::: "memory");
  __builtin_amdgcn_s_barrier();
  __builtin_amdgcn_sched_barrier(0);

  {
    int ring = 0;
    for (int kt = 0; kt < 32; ++kt) {
      int cur = ring;
      int rp2 = (ring == 0) ? 2 : ring - 1;
      if (kt + 2 < 32) BSTAGE(rp2, kt + 2)
      // pin: stage loads issue BEFORE the 16 atten stores, so vmcnt counting holds
      __builtin_amdgcn_sched_barrier(0);

      f32x4 sc[4];
#pragma unroll
      for (int t8 = 0; t8 < 4; ++t8) {
        int kr = t8 * 16 + l15;
        bf16x8 kf0 = KVl[cur][kr * 8 + ((l4) ^ (kr & 7))];
        bf16x8 kf1 = KVl[cur][kr * 8 + ((4 + l4) ^ (kr & 7))];
        f32x4 a_ = {0.f, 0.f, 0.f, 0.f};
        a_ = __builtin_amdgcn_mfma_f32_16x16x32_bf16(qf0, kf0, a_, 0, 0, 0);
        a_ = __builtin_amdgcn_mfma_f32_16x16x32_bf16(qf1, kf1, a_, 0, 0, 0);
        sc[t8] = a_;
      }

#pragma unroll
      for (int t8 = 0; t8 < 4; ++t8) {
#pragma unroll
        for (int r = 0; r < 4; ++r) {
          float p = exp2_hw(sc[t8][r]) * inv_l[r];
          aRow[(size_t)(l4 * 4 + r) * S_ + kt * 64 + t8 * 16 + l15] = p;
          PlW[(l4 * 4 + r) * 88 + t8 * 16 + l15] = (__bf16)p;
        }
      }

#pragma unroll
      for (int kc = 0; kc < 2; ++kc) {
        bf16x8 pa = Pl[w * 176 + l15 * 11 + kc * 4 + l4];
#pragma unroll
        for (int dt = 0; dt < 4; ++dt) {
          int vr = dt * 16 + l15;
          bf16x8 vf = KVl[cur][512 + vr * 8 + ((kc * 4 + l4) ^ (vr & 7))];
          ctx[dt] = __builtin_amdgcn_mfma_f32_16x16x32_bf16(pa, vf, ctx[dt], 0, 0, 0);
        }
      }

      if (kt < 31) {
        // steady state: newest-18 = L(t+2)2 + St(t)16 -> forces L(t+1) landed
        asm volatile("s_waitcnt vmcnt(18)" ::: "memory");
        __builtin_amdgcn_s_barrier();
        __builtin_amdgcn_sched_barrier(0);
      }
      ring = (ring == 2) ? 0 : ring + 1;
    }
  }
#undef BSTAGE

  int b = bh >> 4, h = bh & 15;
#pragma unroll
  for (int dt = 0; dt < 4; ++dt) {
#pragma unroll
    for (int r = 0; r < 4; ++r) {
      size_t row = (size_t)b * S_ + q0 + l4 * 4 + r;
      ctxb[row * D_ + h * 64 + dt * 16 + l15] = (__bf16)ctx[dt][r];
    }
  }
}

// ---------------- K3: output projection -> fp32 d_out (XCD-clustered) ------
__global__ __launch_bounds__(256, 3) void k_out(
    const __bf16* __restrict__ X, const __bf16* __restrict__ W,
    const float* __restrict__ bias, float* __restrict__ O)
{
  __shared__ bf16x8 As[3][512];
  __shared__ bf16x8 Bs[3][512];

  int o = (blockIdx.x % 32) * 8 + blockIdx.x / 32;  // bijective, 256 = 32*8
  int nb = o & 7, mb = o >> 3;

  int t = threadIdx.x, lane = t & 63, w = t >> 6;
  int l15 = lane & 15, l4 = lane >> 4;
  int wr = w >> 1, wc = w & 1;
  int m0 = mb * 128, n0 = nb * 128;

  int srow = t >> 2, sc = t & 3;
  int ldsoff = __builtin_amdgcn_readfirstlane(w * 1024);
  const __bf16* Xs = X + (size_t)(m0 + srow) * 1024 + sc * 8;
  const __bf16* Wsp = W + (size_t)(n0 + srow) * 1024 + sc * 8;

#define PSTAGE(buf, kt)                                                        \
  {                                                                            \
    _Pragma("unroll")                                                          \
    for (int i = 0; i < 2; ++i) {                                              \
      int lo = __builtin_amdgcn_readfirstlane(i * 4096 + ldsoff);              \
      g2l16(Xs + (size_t)i * 64 * 1024 + (kt) * 32, (char*)As[buf] + lo);      \
      g2l16(Wsp + (size_t)i * 64 * 1024 + (kt) * 32, (char*)Bs[buf] + lo);     \
    }                                                                          \
  }

  f32x4 acc[4][4] = {};

  PSTAGE(0, 0)
  PSTAGE(1, 1)
  asm volatile("s_waitcnt vmcnt(4)" ::: "memory");
  __builtin_amdgcn_s_barrier();
  __builtin_amdgcn_sched_barrier(0);

  int ring = 0;
  for (int kt = 0; kt < 32; ++kt) {
    int cur = ring;
    int rp2 = (ring == 0) ? 2 : ring - 1;
    if (kt + 2 < 32) PSTAGE(rp2, kt + 2)
    __builtin_amdgcn_sched_barrier(0);

    bf16x8 af[4], bfr[4];
#pragma unroll
    for (int i = 0; i < 4; ++i) af[i] = As[cur][(wr * 64 + i * 16 + l15) * 4 + l4];
#pragma unroll
    for (int j = 0; j < 4; ++j) bfr[j] = Bs[cur][(wc * 64 + j * 16 + l15) * 4 + l4];
#pragma unroll
    for (int i = 0; i < 4; ++i)
#pragma unroll
      for (int j = 0; j < 4; ++j)
        acc[i][j] = __builtin_amdgcn_mfma_f32_16x16x32_bf16(af[i], bfr[j], acc[i][j], 0, 0, 0);

    if (kt < 30) {
      asm volatile("s_waitcnt vmcnt(4)" ::: "memory");
      __builtin_amdgcn_s_barrier();
      __builtin_amdgcn_sched_barrier(0);
    } else if (kt == 30) {
      asm volatile("s_waitcnt vmcnt(0)" ::: "memory");
      __builtin_amdgcn_s_barrier();
      __builtin_amdgcn_sched_barrier(0);
    }
    ring = (ring == 2) ? 0 : ring + 1;
  }
#undef PSTAGE

#pragma unroll
  for (int j = 0; j < 4; ++j) {
    int col = n0 + wc * 64 + j * 16 + l15;
    float bv_ = bias[col];
#pragma unroll
    for (int i = 0; i < 4; ++i) {
#pragma unroll
      for (int r = 0; r < 4; ++r) {
        int row = m0 + wr * 64 + i * 16 + l4 * 4 + r;
        O[(size_t)row * 1024 + col] = acc[i][j][r] + bv_;
      }
    }
  }
}

// ---------------- launch ----------------
extern "C" void kernel_launch(void* const* d_in, const int* in_sizes, int n_in,
                              void* d_out, int out_size, void* d_ws, size_t ws_size,
                              hipStream_t stream)
{
  const float* q  = (const float*)d_in[0];
  const float* k  = (const float*)d_in[1];
  const float* v  = (const float*)d_in[2];
  const float* Wq = (const float*)d_in[3];
  const float* bq = (const float*)d_in[4];
  const float* Wk = (const float*)d_in[5];
  const float* bk = (const float*)d_in[6];
  const float* Wv = (const float*)d_in[7];
  const float* bv = (const float*)d_in[8];
  const float* Wo = (const float*)d_in[9];
  const float* bo = (const float*)d_in[10];

  const size_t NBSD = (size_t)B_ * S_ * D_;   // 4194304
  const size_t NDD  = (size_t)D_ * D_;        // 1048576

  float* out = (float*)d_out;
  float* atten = out + NBSD;

  if (ws_size < (4 * NDD + 4 * NBSD) * 2) return;  // ~41.9 MB needed

  __bf16* ws = (__bf16*)d_ws;
  __bf16* Wqb = ws;
  __bf16* Wkb = Wqb + NDD;
  __bf16* Wvb = Wkb + NDD;
  __bf16* Wob = Wvb + NDD;
  __bf16* Qh  = Wob + NDD;
  __bf16* Kh  = Qh + NBSD;
  __bf16* VhT = Kh + NBSD;
  __bf16* ctxb = VhT + NBSD;

  CvtArgs ca;
  ca.s[0] = Wq; ca.d[0] = Wqb;
  ca.s[1] = Wk; ca.d[1] = Wkb;
  ca.s[2] = Wv; ca.d[2] = Wvb;
  ca.s[3] = Wo; ca.d[3] = Wob;

  k_cvt<<<dim3(512, 4), 256, 0, stream>>>(ca);
  k_proj<<<dim3(768), 256, 0, stream>>>(q, k, v, Wqb, Wkb, Wvb,
                                        bq, bk, bv, Qh, Kh, VhT);
  k_attn<<<dim3(512), 512, 0, stream>>>(Qh, Kh, VhT, atten, ctxb);
  k_out<<<dim3(256), 256, 0, stream>>>(ctxb, Wob, bo, out);
}